// Round 1
// baseline (1692.434 us; speedup 1.0000x reference)
//
#include <hip/hip_runtime.h>

#define EPSV 1e-5f

static inline int cdiv(int a, int b) { return (a + b - 1) / b; }

__global__ void zero_kernel(float* __restrict__ p, int n) {
  int i = blockIdx.x * blockDim.x + threadIdx.x;
  if (i < n) p[i] = 0.f;
}

// One thread per (output row, output channel). Block = 256 threads = (256/CO) rows.
// Writes raw conv output y and atomically accumulates per-channel sum / sumsq into
// stats[0:64) / stats[64:128).
template<int CI, int CO>
__global__ __launch_bounds__(256) void conv_kernel(
    const float* __restrict__ f, const int* __restrict__ nbr,
    const float* __restrict__ w, float* __restrict__ y,
    float* __restrict__ stats, int nout) {
  constexpr int ROWS = 256 / CO;
  const int o = threadIdx.x % CO;
  const int r = threadIdx.x / CO;
  const int n = blockIdx.x * ROWS + r;
  float acc = 0.f;
  if (n < nout) {
    const int* nb = nbr + (long)n * 27;
#pragma unroll 1
    for (int k = 0; k < 27; ++k) {
      int idx = nb[k];
      if (idx >= 0) {
        const float* fr = f + (long)idx * CI;
        const float* wk = w + (long)k * CI * CO + o;
#pragma unroll
        for (int c = 0; c < CI; ++c)
          acc = fmaf(fr[c], wk[(long)c * CO], acc);
      }
    }
    y[(long)n * CO + o] = acc;
  }
  // block-level BN statistics reduction
  __shared__ float s_sum[CO];
  __shared__ float s_sq[CO];
  if (threadIdx.x < CO) { s_sum[threadIdx.x] = 0.f; s_sq[threadIdx.x] = 0.f; }
  __syncthreads();
  float a = (n < nout) ? acc : 0.f;
  atomicAdd(&s_sum[o], a);
  atomicAdd(&s_sq[o], a * a);
  __syncthreads();
  if (threadIdx.x < CO) {
    atomicAdd(&stats[threadIdx.x], s_sum[threadIdx.x]);
    atomicAdd(&stats[64 + threadIdx.x], s_sq[threadIdx.x]);
  }
}

// Applies training-mode BN (+ ReLU) and optional residual add (skip != nullptr).
template<int CO>
__global__ __launch_bounds__(256) void bn_relu_kernel(
    const float* __restrict__ y, const float* __restrict__ stats,
    const float* __restrict__ g, const float* __restrict__ b,
    const float* __restrict__ skip, float* __restrict__ out, int nout) {
  int i = blockIdx.x * blockDim.x + threadIdx.x;
  int total = nout * CO;
  if (i >= total) return;
  int o = i % CO;
  float inv_n = 1.f / (float)nout;
  float mu = stats[o] * inv_n;
  float var = stats[64 + o] * inv_n - mu * mu;
  float v = (y[i] - mu) * rsqrtf(var + EPSV) * g[o] + b[o];
  v = fmaxf(v, 0.f);
  if (skip) v += skip[i];
  out[i] = v;
}

// out[n,j] = sum_c x[n,c] * w[j,c]   (8x8)
__global__ __launch_bounds__(256) void linear_kernel(
    const float* __restrict__ x, const float* __restrict__ w,
    float* __restrict__ out, int n0) {
  int i = blockIdx.x * blockDim.x + threadIdx.x;
  if (i >= n0 * 8) return;
  int n = i >> 3, j = i & 7;
  const float* xr = x + n * 8;
  const float* wr = w + j * 8;
  float acc = 0.f;
#pragma unroll
  for (int c = 0; c < 8; ++c) acc = fmaf(xr[c], wr[c], acc);
  out[i] = acc;
}

extern "C" void kernel_launch(void* const* d_in, const int* in_sizes, int n_in,
                              void* d_out, int out_size, void* d_ws, size_t ws_size,
                              hipStream_t stream) {
  // ---- inputs (setup_inputs dict order) ----
  const float* feats   = (const float*)d_in[0];
  const int* nbr0      = (const int*)d_in[1];
  const int* nbr_d01   = (const int*)d_in[2];
  const int* nbr1      = (const int*)d_in[3];
  const int* nbr_d12   = (const int*)d_in[4];
  const int* nbr2      = (const int*)d_in[5];
  const int* nbr_d23   = (const int*)d_in[6];
  const int* nbr3      = (const int*)d_in[7];
  const int* nbr_u32   = (const int*)d_in[8];
  const int* nbr_u21   = (const int*)d_in[9];
  const int* nbr_u10   = (const int*)d_in[10];
  const float* w[10];
  const float* g[10];
  const float* b[10];
  for (int i = 0; i < 10; ++i) {
    w[i] = (const float*)d_in[11 + 3 * i];
    g[i] = (const float*)d_in[12 + 3 * i];
    b[i] = (const float*)d_in[13 + 3 * i];
  }
  const float* lin_w = (const float*)d_in[41];

  const int N0 = in_sizes[0] / 16;
  const int N1 = in_sizes[2] / 27;
  const int N2 = in_sizes[4] / 27;
  const int N3 = in_sizes[6] / 27;

  // ---- workspace layout (floats) ----
  float* ws    = (float*)d_ws;
  float* stats = ws;                       // 10 slots x 128 floats
  float* c0f   = stats + 10 * 128;         // N0*8   (skip, kept)
  float* t1    = c0f + (size_t)N0 * 8;     // N1*16
  float* c2f   = t1 + (size_t)N1 * 16;     // N1*16  (skip, kept)
  float* t2    = c2f + (size_t)N1 * 16;    // N2*32
  float* c4f   = t2 + (size_t)N2 * 32;     // N2*32  (skip, kept)
  float* t3    = c4f + (size_t)N2 * 32;    // N3*64
  float* t4    = t3 + (size_t)N3 * 64;     // N3*64
  float* t5    = t2;                       // reuse (t2 dead after conv4)
  float* t6    = t1;                       // reuse (t1 dead after conv2)

  float* out0 = (float*)d_out;                 // linear output; also conv9 y staging
  float* x0   = (float*)d_out + (size_t)N0 * 8; // second output: x itself

  zero_kernel<<<cdiv(10 * 128, 256), 256, 0, stream>>>(stats, 10 * 128);

  // conv0: 16->8 @ N0
  conv_kernel<16, 8><<<cdiv(N0, 32), 256, 0, stream>>>(feats, nbr0, w[0], c0f, stats + 0 * 128, N0);
  bn_relu_kernel<8><<<cdiv(N0 * 8, 256), 256, 0, stream>>>(c0f, stats + 0 * 128, g[0], b[0], nullptr, c0f, N0);

  // conv1: 8->16 down to N1
  conv_kernel<8, 16><<<cdiv(N1, 16), 256, 0, stream>>>(c0f, nbr_d01, w[1], t1, stats + 1 * 128, N1);
  bn_relu_kernel<16><<<cdiv(N1 * 16, 256), 256, 0, stream>>>(t1, stats + 1 * 128, g[1], b[1], nullptr, t1, N1);

  // conv2: 16->16 @ N1
  conv_kernel<16, 16><<<cdiv(N1, 16), 256, 0, stream>>>(t1, nbr1, w[2], c2f, stats + 2 * 128, N1);
  bn_relu_kernel<16><<<cdiv(N1 * 16, 256), 256, 0, stream>>>(c2f, stats + 2 * 128, g[2], b[2], nullptr, c2f, N1);

  // conv3: 16->32 down to N2
  conv_kernel<16, 32><<<cdiv(N2, 8), 256, 0, stream>>>(c2f, nbr_d12, w[3], t2, stats + 3 * 128, N2);
  bn_relu_kernel<32><<<cdiv(N2 * 32, 256), 256, 0, stream>>>(t2, stats + 3 * 128, g[3], b[3], nullptr, t2, N2);

  // conv4: 32->32 @ N2
  conv_kernel<32, 32><<<cdiv(N2, 8), 256, 0, stream>>>(t2, nbr2, w[4], c4f, stats + 4 * 128, N2);
  bn_relu_kernel<32><<<cdiv(N2 * 32, 256), 256, 0, stream>>>(c4f, stats + 4 * 128, g[4], b[4], nullptr, c4f, N2);

  // conv5: 32->64 down to N3
  conv_kernel<32, 64><<<cdiv(N3, 4), 256, 0, stream>>>(c4f, nbr_d23, w[5], t3, stats + 5 * 128, N3);
  bn_relu_kernel<64><<<cdiv(N3 * 64, 256), 256, 0, stream>>>(t3, stats + 5 * 128, g[5], b[5], nullptr, t3, N3);

  // conv6: 64->64 @ N3
  conv_kernel<64, 64><<<cdiv(N3, 4), 256, 0, stream>>>(t3, nbr3, w[6], t4, stats + 6 * 128, N3);
  bn_relu_kernel<64><<<cdiv(N3 * 64, 256), 256, 0, stream>>>(t4, stats + 6 * 128, g[6], b[6], nullptr, t4, N3);

  // conv7: 64->32 up to N2, then x2 = c4f + relu(bn(y))
  conv_kernel<64, 32><<<cdiv(N2, 8), 256, 0, stream>>>(t4, nbr_u32, w[7], t5, stats + 7 * 128, N2);
  bn_relu_kernel<32><<<cdiv(N2 * 32, 256), 256, 0, stream>>>(t5, stats + 7 * 128, g[7], b[7], c4f, t5, N2);

  // conv8: 32->16 up to N1, then x1 = c2f + relu(bn(y))
  conv_kernel<32, 16><<<cdiv(N1, 16), 256, 0, stream>>>(t5, nbr_u21, w[8], t6, stats + 8 * 128, N1);
  bn_relu_kernel<16><<<cdiv(N1 * 16, 256), 256, 0, stream>>>(t6, stats + 8 * 128, g[8], b[8], c2f, t6, N1);

  // conv9: 16->8 up to N0, then x0 = c0f + relu(bn(y))
  // raw y staged in out0 (overwritten by linear kernel afterwards)
  conv_kernel<16, 8><<<cdiv(N0, 32), 256, 0, stream>>>(t6, nbr_u10, w[9], out0, stats + 9 * 128, N0);
  bn_relu_kernel<8><<<cdiv(N0 * 8, 256), 256, 0, stream>>>(out0, stats + 9 * 128, g[9], b[9], c0f, x0, N0);

  // final linear: out0 = x0 @ lin_w.T
  linear_kernel<<<cdiv(N0 * 8, 256), 256, 0, stream>>>(x0, lin_w, out0, N0);
}